// Round 8
// baseline (298.727 us; speedup 1.0000x reference)
//
#include <hip/hip_runtime.h>
#include <cstdint>

// Fused attention, B=2 S=2048 E=1024 H=16 d=64.
// R8: (1) attn = 2-way key split (exact combine, no online max) with
// single-buffered LDS (18.4 KB) + register-prefetch staging -> 8 blocks/CU
// = 16 waves/CU (grid 2048), double R5/R7's 8. (2) gemm_qkv staging switched
// from global_load_lds-between-barriers (full vmcnt(0) drain each iter) to
// register prefetch: loads issue at iter top, ds_write after 2nd barrier.

typedef __bf16 bf16x8 __attribute__((ext_vector_type(8)));
typedef short s16x4 __attribute__((ext_vector_type(4)));
typedef float f32x4 __attribute__((ext_vector_type(4)));

__device__ __forceinline__ unsigned short f32_to_bf16_rne(float f) {
    unsigned int u = __builtin_bit_cast(unsigned int, f);
    u += 0x7FFF + ((u >> 16) & 1);
    return (unsigned short)(u >> 16);
}

// pack 2 f32 -> 2 bf16 (truncate) in one v_perm_b32
__device__ __forceinline__ unsigned int pack_bf16_trunc(float a, float b) {
    unsigned int ua = __builtin_bit_cast(unsigned int, a);
    unsigned int ub = __builtin_bit_cast(unsigned int, b);
    return __builtin_amdgcn_perm(ub, ua, 0x07060302u);  // [b.hi16 : a.hi16]
}

// One launch converting x (1048576 f4), w_in (786432 f4), w_out (262144 f4).
__global__ void cvt_all(const float* __restrict__ x, const float* __restrict__ wi,
                        const float* __restrict__ wo, unsigned short* __restrict__ xb,
                        unsigned short* __restrict__ wib, unsigned short* __restrict__ wob) {
    int i = blockIdx.x * blockDim.x + threadIdx.x;  // 0 .. 2097151
    const float* src; unsigned short* dst; int off;
    if (i < 1048576)            { src = x;  dst = xb;  off = i; }
    else if (i < 1048576 + 786432) { src = wi; dst = wib; off = i - 1048576; }
    else                        { src = wo; dst = wob; off = i - (1048576 + 786432); }
    float4 v = ((const float4*)src)[off];
    ushort4 o;
    o.x = f32_to_bf16_rne(v.x); o.y = f32_to_bf16_rne(v.y);
    o.z = f32_to_bf16_rne(v.z); o.w = f32_to_bf16_rne(v.w);
    ((ushort4*)dst)[off] = o;
}

// GEMM1: C[4096][3072] = X[4096][1024] * W[3072][1024]^T + bias
// Register-prefetch staging: global->VGPR at iter top, ds_write after the
// read-barrier, so load latency hides behind ds_read+MFMA (no vmcnt(0) drain
// at the barrier). Epilogue routes Q (scaled, log2), K, V^T.
__launch_bounds__(256, 3)
__global__ void gemm_qkv(const unsigned short* __restrict__ X,
                         const unsigned short* __restrict__ W,
                         const float* __restrict__ bias,
                         unsigned short* __restrict__ Qp,
                         unsigned short* __restrict__ Kp,
                         unsigned short* __restrict__ Vt) {
    __shared__ __align__(16) unsigned short As[128 * 32];
    __shared__ __align__(16) unsigned short Bs[128 * 32];
    const int t = threadIdx.x;
    const int w = t >> 6, lane = t & 63, quad = lane >> 4, l16 = lane & 15;
    const int wm = (w >> 1) * 64, wn = (w & 1) * 64;
    const int m0 = blockIdx.y * 128, n0 = blockIdx.x * 128;

    // staging coords: 2 chunks of 16B for As, 2 for Bs per thread
    const int c0 = t, c1 = t + 256;
    const int r0 = c0 >> 2, cc0 = (c0 & 3) * 8;
    const int r1 = c1 >> 2, cc1 = (c1 & 3) * 8;

    f32x4 acc[4][4] = {};

    // preload kt=0
    uint4 xa0 = *(const uint4*)&X[(m0 + r0) * 1024 + cc0];
    uint4 xa1 = *(const uint4*)&X[(m0 + r1) * 1024 + cc1];
    uint4 wb0 = *(const uint4*)&W[(n0 + r0) * 1024 + cc0];
    uint4 wb1 = *(const uint4*)&W[(n0 + r1) * 1024 + cc1];
    *(uint4*)&As[c0 * 8] = xa0;  *(uint4*)&As[c1 * 8] = xa1;
    *(uint4*)&Bs[c0 * 8] = wb0;  *(uint4*)&Bs[c1 * 8] = wb1;

    for (int it = 0; it < 32; ++it) {
        __syncthreads();                    // staged writes visible
        const bool pf = (it != 31);
        if (pf) {
            int kt = (it + 1) * 32;
            xa0 = *(const uint4*)&X[(m0 + r0) * 1024 + kt + cc0];
            xa1 = *(const uint4*)&X[(m0 + r1) * 1024 + kt + cc1];
            wb0 = *(const uint4*)&W[(n0 + r0) * 1024 + kt + cc0];
            wb1 = *(const uint4*)&W[(n0 + r1) * 1024 + kt + cc1];
        }
        bf16x8 af[4], bw[4];
#pragma unroll
        for (int mi = 0; mi < 4; ++mi)
            af[mi] = *(const bf16x8*)&As[(wm + mi * 16 + l16) * 32 + quad * 8];
#pragma unroll
        for (int ni = 0; ni < 4; ++ni)
            bw[ni] = *(const bf16x8*)&Bs[(wn + ni * 16 + l16) * 32 + quad * 8];
#pragma unroll
        for (int mi = 0; mi < 4; ++mi)
#pragma unroll
            for (int ni = 0; ni < 4; ++ni)
                acc[mi][ni] = __builtin_amdgcn_mfma_f32_16x16x32_bf16(af[mi], bw[ni], acc[mi][ni], 0, 0, 0);
        __syncthreads();                    // all LDS reads done
        if (pf) {
            *(uint4*)&As[c0 * 8] = xa0;  *(uint4*)&As[c1 * 8] = xa1;
            *(uint4*)&Bs[c0 * 8] = wb0;  *(uint4*)&Bs[c1 * 8] = wb1;
        }
    }

    const float QSCALE = 0.125f * 1.44269504089f;  // fold 1/sqrt(d) and log2(e)
#pragma unroll
    for (int mi = 0; mi < 4; ++mi) {
#pragma unroll
        for (int ni = 0; ni < 4; ++ni) {
            int col = n0 + wn + ni * 16 + l16;
            float bv = bias[col];
            int which = col >> 10;
            int hc = col & 1023;
            int h = hc >> 6, d = hc & 63;
            int row0 = m0 + wm + mi * 16 + quad * 4;   // 4-aligned, no 2048 cross
            int b = row0 >> 11, s0 = row0 & 2047;
            int bh = b * 16 + h;
            if (which == 2) {
                // V^T: d fixed per lane, 4 consecutive s -> one 8B store
                ushort4 pk;
                pk.x = f32_to_bf16_rne(acc[mi][ni][0] + bv);
                pk.y = f32_to_bf16_rne(acc[mi][ni][1] + bv);
                pk.z = f32_to_bf16_rne(acc[mi][ni][2] + bv);
                pk.w = f32_to_bf16_rne(acc[mi][ni][3] + bv);
                *(ushort4*)&Vt[(bh * 64 + d) * 2048 + s0] = pk;
            } else if (which == 0) {
#pragma unroll
                for (int r = 0; r < 4; ++r)
                    Qp[(bh * 2048 + s0 + r) * 64 + d] =
                        f32_to_bf16_rne((acc[mi][ni][r] + bv) * QSCALE);
            } else {
#pragma unroll
                for (int r = 0; r < 4; ++r)
                    Kp[(bh * 2048 + s0 + r) * 64 + d] = f32_to_bf16_rne(acc[mi][ni][r] + bv);
            }
        }
    }
}

// Flash attention, S^T orientation, no online max, 2-way key split.
// 1 block = (bh, split, 64 queries): 2 waves x 32 queries over 1024 keys.
// Single-buffered K/V LDS (18.4 KB) + register prefetch -> 8 blocks/CU.
// PV consumes packed s_acc directly via 16x16x16 MFMA (no P round-trip).
#define LDP 72  // padded LDS row: 144 B = 4 mod 32 banks
__launch_bounds__(128, 4)
__global__ void attn_ks(const unsigned short* __restrict__ Qp, const unsigned short* __restrict__ Kp,
                        const unsigned short* __restrict__ Vt,
                        float* __restrict__ Po, float* __restrict__ Pl) {
    __shared__ __align__(16) unsigned short Ks[64 * LDP];  // [key][d]
    __shared__ __align__(16) unsigned short Vs[64 * LDP];  // [d][key]
    const int t = threadIdx.x, w = t >> 6, lane = t & 63, quad = lane >> 4, l16 = lane & 15;
    const int bh = blockIdx.x;           // 0..31
    const int qb = blockIdx.y;           // 0..31 (64-query tiles)
    const int split = blockIdx.z;        // 0..1
    const unsigned short* Qh = Qp + bh * (2048 * 64);
    const unsigned short* Kh = Kp + bh * (2048 * 64) + split * 1024 * 64;
    const unsigned short* Vh = Vt + bh * (64 * 2048) + split * 1024;

    // Q as B-operand (K=32): lane holds Q[q = nq*16+l16][d = ks*32+quad*8 ..+7]
    bf16x8 qf[2][2];
#pragma unroll
    for (int nq = 0; nq < 2; ++nq)
#pragma unroll
        for (int ks = 0; ks < 2; ++ks) {
            int row = qb * 64 + w * 32 + nq * 16 + l16;
            qf[nq][ks] = *(const bf16x8*)&Qh[row * 64 + ks * 32 + quad * 8];
        }

    // staging: 128 threads x 4 16B chunks each for K and V
    f32x4 o_acc[4][2] = {};   // O^T: [dm][nq], C layout: d=dm*16+quad*4+reg, q=nq*16+l16
    float l_lane[2] = {0.f, 0.f};

    uint4 kn[4], vn[4];
#pragma unroll
    for (int i = 0; i < 4; ++i) {
        int c = t + 128 * i;   // 0..511
        int r = c >> 3, cc = (c & 7) * 8;
        *(uint4*)&Ks[r * LDP + cc] = *(const uint4*)&Kh[r * 64 + cc];
        *(uint4*)&Vs[r * LDP + cc] = *(const uint4*)&Vh[r * 2048 + cc];
    }

    for (int it = 0; it < 16; ++it) {
        __syncthreads();                     // staged K/V visible
        const bool pf = (it != 15);
        if (pf) {
            int ktn = (it + 1) * 64;
#pragma unroll
            for (int i = 0; i < 4; ++i) {
                int c = t + 128 * i;
                int r = c >> 3, cc = (c & 7) * 8;
                kn[i] = *(const uint4*)&Kh[(ktn + r) * 64 + cc];
                vn[i] = *(const uint4*)&Vh[r * 2048 + ktn + cc];
            }
        }

        // S^T = K * Q^T  (row = key, col = query), K=32 MFMA
        f32x4 s_acc[4][2] = {};
#pragma unroll
        for (int ks = 0; ks < 2; ++ks)
#pragma unroll
            for (int mi = 0; mi < 4; ++mi) {
                bf16x8 kf = *(const bf16x8*)&Ks[(mi * 16 + l16) * LDP + ks * 32 + quad * 8];
#pragma unroll
                for (int nq = 0; nq < 2; ++nq)
                    s_acc[mi][nq] = __builtin_amdgcn_mfma_f32_16x16x32_bf16(kf, qf[nq][ks], s_acc[mi][nq], 0, 0, 0);
            }

        // p = exp2(s) direct; packed s_acc IS the B-operand of the K=16 MFMA:
        // B[n=l16][k=quad*4+j] == S^T[key=mi*16+quad*4+r][q=l16]
        s16x4 bq[4][2];
#pragma unroll
        for (int nq = 0; nq < 2; ++nq) {
            float rsum = 0.f;
#pragma unroll
            for (int mi = 0; mi < 4; ++mi) {
                float p0 = exp2f(s_acc[mi][nq][0]);
                float p1 = exp2f(s_acc[mi][nq][1]);
                float p2 = exp2f(s_acc[mi][nq][2]);
                float p3 = exp2f(s_acc[mi][nq][3]);
                rsum += (p0 + p1) + (p2 + p3);
                uint2 pk;
                pk.x = pack_bf16_trunc(p0, p1);
                pk.y = pack_bf16_trunc(p2, p3);
                bq[mi][nq] = __builtin_bit_cast(s16x4, pk);
            }
            l_lane[nq] += rsum;  // per-lane partial; cross-quad reduce deferred
        }

        // O^T += V^T * P^T via 16x16x16 MFMA; A = V^T[d=dm*16+l16][key=kt4*16+quad*4..+3]
#pragma unroll
        for (int dm = 0; dm < 4; ++dm)
#pragma unroll
            for (int kt4 = 0; kt4 < 4; ++kt4) {
                s16x4 av = __builtin_bit_cast(s16x4,
                    *(const uint2*)&Vs[(dm * 16 + l16) * LDP + kt4 * 16 + quad * 4]);
#pragma unroll
                for (int nq = 0; nq < 2; ++nq)
                    o_acc[dm][nq] = __builtin_amdgcn_mfma_f32_16x16x16bf16_1k(av, bq[kt4][nq], o_acc[dm][nq], 0, 0, 0);
            }

        __syncthreads();                     // all LDS reads done
        if (pf) {
#pragma unroll
            for (int i = 0; i < 4; ++i) {
                int c = t + 128 * i;
                int r = c >> 3, cc = (c & 7) * 8;
                *(uint4*)&Ks[r * LDP + cc] = kn[i];
                *(uint4*)&Vs[r * LDP + cc] = vn[i];
            }
        }
    }

    // epilogue: fp32 partials. Po[split][bh][q][d], Pl[split][bh][q]
#pragma unroll
    for (int nq = 0; nq < 2; ++nq) {
        float l = l_lane[nq];
        l += __shfl_xor(l, 16);
        l += __shfl_xor(l, 32);
        int q = qb * 64 + w * 32 + nq * 16 + l16;
        size_t base = ((size_t)(split * 32 + bh) * 2048 + q) * 64;
#pragma unroll
        for (int dm = 0; dm < 4; ++dm)
            *(float4*)&Po[base + dm * 16 + quad * 4] = __builtin_bit_cast(float4, o_acc[dm][nq]);
        if (quad == 0)
            Pl[(split * 32 + bh) * 2048 + q] = l;
    }
}

// Combine: A2[tok][h*64+d] = (O0+O1)/(l0+l1), bf16 out.
__global__ void attn_combine(const float* __restrict__ Po, const float* __restrict__ Pl,
                             unsigned short* __restrict__ A2) {
    int i = blockIdx.x * blockDim.x + threadIdx.x;  // 0 .. 32*2048*16-1
    int bh = i >> 15;
    int rem = i & 32767;
    int q = rem >> 4;
    int d = (rem & 15) * 4;
    size_t base = ((size_t)bh * 2048 + q) * 64 + d;
    const size_t SPLIT = (size_t)32 * 2048 * 64;
    float4 o0 = *(const float4*)&Po[base];
    float4 o1 = *(const float4*)&Po[base + SPLIT];
    float l = Pl[bh * 2048 + q] + Pl[32 * 2048 + bh * 2048 + q];
    float rl = 1.0f / l;
    int tok = (bh >> 4) * 2048 + q;
    int col = (bh & 15) * 64 + d;
    ushort4 o;
    o.x = f32_to_bf16_rne((o0.x + o1.x) * rl);
    o.y = f32_to_bf16_rne((o0.y + o1.y) * rl);
    o.z = f32_to_bf16_rne((o0.z + o1.z) * rl);
    o.w = f32_to_bf16_rne((o0.w + o1.w) * rl);
    *(ushort4*)&A2[(size_t)tok * 1024 + col] = o;
}

// GEMM2: out[4096][1024] = A2[4096][1024] * W[1024][1024]^T + bias (fp32 out)
// 128x64 tiles, register-prefetch staging like gemm_qkv.
__launch_bounds__(256, 3)
__global__ void gemm_out_k(const unsigned short* __restrict__ A, const unsigned short* __restrict__ W,
                           const float* __restrict__ bias, float* __restrict__ out) {
    __shared__ __align__(16) unsigned short As[128 * 32];
    __shared__ __align__(16) unsigned short Bs[64 * 32];
    const int t = threadIdx.x;
    const int w = t >> 6, lane = t & 63, quad = lane >> 4, l16 = lane & 15;
    const int wm = (w >> 1) * 64, wn = (w & 1) * 32;
    const int m0 = blockIdx.y * 128, n0 = blockIdx.x * 64;

    const int c0 = t, c1 = t + 256;
    const int ra0 = c0 >> 2, ca0 = (c0 & 3) * 8;
    const int ra1 = c1 >> 2, ca1 = (c1 & 3) * 8;

    f32x4 acc[4][2] = {};

    uint4 aa0 = *(const uint4*)&A[(m0 + ra0) * 1024 + ca0];
    uint4 aa1 = *(const uint4*)&A[(m0 + ra1) * 1024 + ca1];
    uint4 wb0 = *(const uint4*)&W[(n0 + ra0) * 1024 + ca0];   // ra0<64 rows only used
    if (ra0 < 64) *(uint4*)&Bs[c0 * 8] = wb0;
    *(uint4*)&As[c0 * 8] = aa0;  *(uint4*)&As[c1 * 8] = aa1;

    for (int it = 0; it < 32; ++it) {
        __syncthreads();
        const bool pf = (it != 31);
        if (pf) {
            int kt = (it + 1) * 32;
            aa0 = *(const uint4*)&A[(m0 + ra0) * 1024 + kt + ca0];
            aa1 = *(const uint4*)&A[(m0 + ra1) * 1024 + kt + ca1];
            if (ra0 < 64) wb0 = *(const uint4*)&W[(n0 + ra0) * 1024 + kt + ca0];
        }
        bf16x8 af[4], bw[2];
#pragma unroll
        for (int mi = 0; mi < 4; ++mi)
            af[mi] = *(const bf16x8*)&As[(wm + mi * 16 + l16) * 32 + quad * 8];
#pragma unroll
        for (int ni = 0; ni < 2; ++ni)
            bw[ni] = *(const bf16x8*)&Bs[(wn + ni * 16 + l16) * 32 + quad * 8];
#pragma unroll
        for (int mi = 0; mi < 4; ++mi)
#pragma unroll
            for (int ni = 0; ni < 2; ++ni)
                acc[mi][ni] = __builtin_amdgcn_mfma_f32_16x16x32_bf16(af[mi], bw[ni], acc[mi][ni], 0, 0, 0);
        __syncthreads();
        if (pf) {
            *(uint4*)&As[c0 * 8] = aa0;  *(uint4*)&As[c1 * 8] = aa1;
            if (ra0 < 64) *(uint4*)&Bs[c0 * 8] = wb0;
        }
    }

#pragma unroll
    for (int mi = 0; mi < 4; ++mi)
#pragma unroll
        for (int ni = 0; ni < 2; ++ni) {
            int col = n0 + wn + ni * 16 + l16;
            float bv = bias[col];
#pragma unroll
            for (int r = 0; r < 4; ++r) {
                int row = m0 + wm + mi * 16 + quad * 4 + r;
                out[row * 1024 + col] = acc[mi][ni][r] + bv;
            }
        }
}

extern "C" void kernel_launch(void* const* d_in, const int* in_sizes, int n_in,
                              void* d_out, int out_size, void* d_ws, size_t ws_size,
                              hipStream_t stream) {
    const float* x     = (const float*)d_in[0];   // [2,2048,1024]
    const float* w_in  = (const float*)d_in[1];   // [3072,1024]
    const float* b_in  = (const float*)d_in[2];   // [3072]
    const float* w_out = (const float*)d_in[3];   // [1024,1024]
    const float* b_out = (const float*)d_in[4];   // [1024]
    float* out = (float*)d_out;

    char* ws = (char*)d_ws;
    unsigned short* xb  = (unsigned short*)(ws);                      // 8.0 MiB
    unsigned short* wib = (unsigned short*)(ws + 8388608);            // 6.0 MiB
    unsigned short* wob = (unsigned short*)(ws + 14680064);           // 2.0 MiB
    unsigned short* Qp  = (unsigned short*)(ws + 16777216);           // 8.0 MiB
    unsigned short* Kp  = (unsigned short*)(ws + 25165824);           // 8.0 MiB
    unsigned short* Vt  = (unsigned short*)(ws + 33554432);           // 8.0 MiB
    unsigned short* A2  = (unsigned short*)(ws + 41943040);           // 8.0 MiB
    float*          Po  = (float*)(ws + 50331648);                    // 32.0 MiB
    float*          Pl  = (float*)(ws + 50331648 + 33554432);         // 0.5 MiB

    cvt_all<<<8192, 256, 0, stream>>>(x, w_in, w_out, xb, wib, wob);
    gemm_qkv<<<dim3(24, 32), 256, 0, stream>>>(xb, wib, b_in, Qp, Kp, Vt);
    attn_ks<<<dim3(32, 32, 2), 128, 0, stream>>>(Qp, Kp, Vt, Po, Pl);
    attn_combine<<<4096, 256, 0, stream>>>(Po, Pl, A2);
    gemm_out_k<<<dim3(16, 32), 256, 0, stream>>>(A2, wob, b_out, out);
}